// Round 5
// baseline (211.352 us; speedup 1.0000x reference)
//
#include <hip/hip_runtime.h>

#define IN_H 512
#define IN_W 512

// ---------- pre-kernel: build f64 tables in d_ws ----------
// ws[0..31]           : D[l][k] f64 half-DCT table (k=0..3), l-major
// ws[32..32+384)      : qt[(c*8+l)*8+i] as double2 {1/q, q}
__global__ void jpeg_tables(const float* __restrict__ qz,
                            const float* __restrict__ dmtx,
                            double* __restrict__ ws)
{
    const int t = threadIdx.x;
    if (t < 32) ws[t] = (double)dmtx[(t >> 2) * 8 + (t & 3)];
    if (t < 192) {
        const int c = t >> 6, i = (t >> 3) & 7, l = t & 7;
        double v  = (double)qz[t];
        double t1 = rint((rint(v * 255.0) * 50.0 + 50.0) / 100.0); // true div: .5 ties
        double q  = fmin(fmax(t1, 1.0), 255.0);
        const int idx = (c * 8 + l) * 8 + i;
        ws[32 + 2 * idx]     = 1.0 / q;
        ws[32 + 2 * idx + 1] = q;
    }
}

// ---------- main kernel ----------
// Thread = (tile 0..31, j 0..7). A tile's 8 threads are 8 consecutive lanes
// of ONE wave -> the whole per-tile pipeline is wave-local: NO __syncthreads.
// f64 half-table lives in SGPRs (uniform s_load from ws). Transposes go
// through per-tile LDS patches with XOR(2j) rotation (bank-minimal).
__global__ __launch_bounds__(256, 2) void jpeg_kernel(
    const float* __restrict__ in, const double* __restrict__ ws,
    float* __restrict__ out)
{
    __shared__ __align__(16) double Tq[32 * 68];   // 17408 B f64 patches
    __shared__ __align__(16) float  Vt[32 * 68];   //  8704 B f32 patches

    const int t    = threadIdx.x;
    const int tile = t >> 3;
    const int tl   = t & 7;          // row j (stage1) / col l (stage2) / pixel row
    const int blk  = blockIdx.x;
    const int b    = blk >> 7;
    const int rr   = blk & 127;
    const int row0 = (rr >> 1) << 3;
    const int col0 = (rr & 1) << 8;
    const int chs  = IN_H * IN_W;

    // f64 half-table -> SGPRs (uniform indices, readonly pointer)
    double D[8][4];
    #pragma unroll
    for (int l = 0; l < 8; ++l)
        #pragma unroll
        for (int k = 0; k < 4; ++k) D[l][k] = ws[l * 4 + k];
    // f32 half-table: exact f64->f32 round-trip of the original f32 values
    float Dh[8][4];
    #pragma unroll
    for (int l = 0; l < 8; ++l)
        #pragma unroll
        for (int k = 0; k < 4; ++k) Dh[l][k] = (float)D[l][k];

    // ---- load own row (8 px x RGB), YCbCr f64 in-register ----
    double yv[8], hcb[4], hcr[4];
    {
        const float* pin = in + ((b * 3) * IN_H + row0 + tl) * IN_W + col0 + tile * 8;
        float4 r0 = *(const float4*)(pin);
        float4 r1 = *(const float4*)(pin + 4);
        float4 g0 = *(const float4*)(pin + chs);
        float4 g1 = *(const float4*)(pin + chs + 4);
        float4 b0 = *(const float4*)(pin + 2 * chs);
        float4 b1 = *(const float4*)(pin + 2 * chs + 4);
        float rf[8] = {r0.x,r0.y,r0.z,r0.w,r1.x,r1.y,r1.z,r1.w};
        float gf[8] = {g0.x,g0.y,g0.z,g0.w,g1.x,g1.y,g1.z,g1.w};
        float bf[8] = {b0.x,b0.y,b0.z,b0.w,b1.x,b1.y,b1.z,b1.w};
        #pragma unroll
        for (int k = 0; k < 8; ++k) {
            double R = 255.0 * (double)rf[k];
            double G = 255.0 * (double)gf[k];
            double B = 255.0 * (double)bf[k];
            double y  =  0.299*R + 0.587*G + 0.114*B;
            double cb = -0.168735892*R - 0.331264108*G + 0.5*B + 128.0;
            double cr =  0.5*R - 0.418687589*G - 0.081312411*B + 128.0;
            yv[k] = fmin(fmax(y , 0.0), 255.0) - 128.0;
            cb    = fmin(fmax(cb, 0.0), 255.0) - 128.0;
            cr    = fmin(fmax(cr, 0.0), 255.0) - 128.0;
            if ((k & 1) == 0) { hcb[k >> 1] = cb;  hcr[k >> 1] = cr; }
            else              { hcb[k >> 1] += cb; hcr[k >> 1] += cr; }
        }
    }

    double* tp  = &Tq[tile * 68];       // per-tile f64 patch
    float*  vp  = &Vt[tile * 68];       // per-tile f32 patch
    const double2* qtab = (const double2*)(ws + 32);

    float acc[3][8];

    #pragma unroll
    for (int c = 0; c < 3; ++c) {
        // ---- stage1: row DCT of own row -> tr[l], write rotated ----
        double e1[4], o1[4];
        if (c == 0) {
            #pragma unroll
            for (int k = 0; k < 4; ++k) { e1[k] = yv[k] + yv[7-k]; o1[k] = yv[k] - yv[7-k]; }
        } else {
            const double* hv = (c == 1) ? hcb : hcr;
            double A = hv[0] + hv[3], Bv = hv[1] + hv[2];
            double C = hv[0] - hv[3], E  = hv[1] - hv[2];
            e1[0] = A; e1[1] = A; e1[2] = Bv; e1[3] = Bv;
            o1[0] = C; o1[1] = C; o1[2] = E;  o1[3] = E;
        }
        double tr[8];
        #pragma unroll
        for (int l = 0; l < 8; ++l) {
            const double* s = (l & 1) ? o1 : e1;
            tr[l] = D[l][0]*s[0] + D[l][1]*s[1] + D[l][2]*s[2] + D[l][3]*s[3];
        }
        // write pairs (tr[2k],tr[2k+1]) at rotated slot (2k+2j)&7
        #pragma unroll
        for (int k = 0; k < 4; ++k) {
            const int s = (2*k + 2*tl) & 7;
            *(double2*)(tp + tl * 8 + s) = make_double2(tr[2*k], tr[2*k+1]);
        }
        __builtin_amdgcn_wave_barrier();

        // ---- stage2: read own column (unrotate), fold, col DCT + quant ----
        double colv[8];
        #pragma unroll
        for (int j = 0; j < 8; ++j) colv[j] = tp[j * 8 + ((tl + 2*j) & 7)];
        __builtin_amdgcn_wave_barrier();

        double e2[4], o2[4];
        if (c == 0) {
            #pragma unroll
            for (int m = 0; m < 4; ++m) { e2[m] = colv[m] + colv[7-m]; o2[m] = colv[m] - colv[7-m]; }
        } else {
            double T0 = 0.25 * (colv[0] + colv[1]);
            double T1 = 0.25 * (colv[2] + colv[3]);
            double T2 = 0.25 * (colv[4] + colv[5]);
            double T3 = 0.25 * (colv[6] + colv[7]);
            double A = T0 + T3, Bv = T1 + T2, C = T0 - T3, E = T1 - T2;
            e2[0] = A; e2[1] = A; e2[2] = Bv; e2[3] = Bv;
            o2[0] = C; o2[1] = C; o2[2] = E;  o2[3] = E;
        }

        float zo[8];
        {
            const double2* qrow = qtab + (c * 8 + tl) * 8;
            #pragma unroll
            for (int i = 0; i < 8; ++i) {
                const double* s = (i & 1) ? o2 : e2;
                double a64 = D[i][0]*s[0] + D[i][1]*s[1] + D[i][2]*s[2] + D[i][3]*s[3];
                double2 qe = qrow[i];
                zo[i] = (float)(rint(a64 * qe.x) * qe.y);
            }
        }

        // ---- col IDCT in registers: u[x] = sum_i zo[i] * D[i][x] ----
        float u[8];
        {
            float se0 = zo[0]*Dh[0][0] + zo[2]*Dh[2][0] + zo[4]*Dh[4][0] + zo[6]*Dh[6][0];
            float se1 = zo[0]*Dh[0][1] + zo[2]*Dh[2][1] + zo[4]*Dh[4][1] + zo[6]*Dh[6][1];
            float se2 = zo[0]*Dh[0][2] + zo[2]*Dh[2][2] + zo[4]*Dh[4][2] + zo[6]*Dh[6][2];
            float se3 = zo[0]*Dh[0][3] + zo[2]*Dh[2][3] + zo[4]*Dh[4][3] + zo[6]*Dh[6][3];
            float so0 = zo[1]*Dh[1][0] + zo[3]*Dh[3][0] + zo[5]*Dh[5][0] + zo[7]*Dh[7][0];
            float so1 = zo[1]*Dh[1][1] + zo[3]*Dh[3][1] + zo[5]*Dh[5][1] + zo[7]*Dh[7][1];
            float so2 = zo[1]*Dh[1][2] + zo[3]*Dh[3][2] + zo[5]*Dh[5][2] + zo[7]*Dh[7][2];
            float so3 = zo[1]*Dh[1][3] + zo[3]*Dh[3][3] + zo[5]*Dh[5][3] + zo[7]*Dh[7][3];
            u[0]=se0+so0; u[7]=se0-so0;
            u[1]=se1+so1; u[6]=se1-so1;
            u[2]=se2+so2; u[5]=se2-so2;
            u[3]=se3+so3; u[4]=se3-so3;
        }

        // ---- f32 wave-local transpose: Vt[tile][x][l] = u[x] ----
        #pragma unroll
        for (int x = 0; x < 8; ++x) vp[x * 8 + tl] = u[x];
        __builtin_amdgcn_wave_barrier();
        float w2[8];
        {
            float4 wa = *(const float4*)(vp + tl * 8);
            float4 wb = *(const float4*)(vp + tl * 8 + 4);
            w2[0]=wa.x; w2[1]=wa.y; w2[2]=wa.z; w2[3]=wa.w;
            w2[4]=wb.x; w2[5]=wb.y; w2[6]=wb.z; w2[7]=wb.w;
        }
        __builtin_amdgcn_wave_barrier();

        // ---- row IDCT: acc[c][y] = sum_k w2[k] * D[k][y] ----
        {
            float re0 = w2[0]*Dh[0][0] + w2[2]*Dh[2][0] + w2[4]*Dh[4][0] + w2[6]*Dh[6][0];
            float re1 = w2[0]*Dh[0][1] + w2[2]*Dh[2][1] + w2[4]*Dh[4][1] + w2[6]*Dh[6][1];
            float re2 = w2[0]*Dh[0][2] + w2[2]*Dh[2][2] + w2[4]*Dh[4][2] + w2[6]*Dh[6][2];
            float re3 = w2[0]*Dh[0][3] + w2[2]*Dh[2][3] + w2[4]*Dh[4][3] + w2[6]*Dh[6][3];
            float ro0 = w2[1]*Dh[1][0] + w2[3]*Dh[3][0] + w2[5]*Dh[5][0] + w2[7]*Dh[7][0];
            float ro1 = w2[1]*Dh[1][1] + w2[3]*Dh[3][1] + w2[5]*Dh[5][1] + w2[7]*Dh[7][1];
            float ro2 = w2[1]*Dh[1][2] + w2[3]*Dh[3][2] + w2[5]*Dh[5][2] + w2[7]*Dh[7][2];
            float ro3 = w2[1]*Dh[1][3] + w2[3]*Dh[3][3] + w2[5]*Dh[5][3] + w2[7]*Dh[7][3];
            acc[c][0]=re0+ro0; acc[c][7]=re0-ro0;
            acc[c][1]=re1+ro1; acc[c][6]=re1-ro1;
            acc[c][2]=re2+ro2; acc[c][5]=re2-ro2;
            acc[c][3]=re3+ro3; acc[c][4]=re3-ro3;
        }
    }

    // ---- RGB convert + stores (thread owns pixel row tl of its tile) ----
    {
        const int obase = ((b * 3) * IN_H + row0 + tl) * IN_W + col0 + tile * 8;
        float R4[8], G4[8], B4[8];
        #pragma unroll
        for (int y = 0; y < 8; ++y) {
            float im0 = acc[0][y] + 128.0f;
            float im1 = acc[1][y];
            float im2 = acc[2][y];
            float R  = fminf(fmaxf(im0 + 1.402f*im2, 0.0f), 255.0f);
            float G  = fminf(fmaxf(im0 - 0.344136286f*im1 - 0.714136286f*im2, 0.0f), 255.0f);
            float Bv = fminf(fmaxf(im0 + 1.772f*im1, 0.0f), 255.0f);
            R4[y] = rintf(R)  * (1.0f/255.0f);
            G4[y] = rintf(G)  * (1.0f/255.0f);
            B4[y] = rintf(Bv) * (1.0f/255.0f);
        }
        *(float4*)(out + obase)             = make_float4(R4[0],R4[1],R4[2],R4[3]);
        *(float4*)(out + obase + 4)         = make_float4(R4[4],R4[5],R4[6],R4[7]);
        *(float4*)(out + obase + chs)       = make_float4(G4[0],G4[1],G4[2],G4[3]);
        *(float4*)(out + obase + chs + 4)   = make_float4(G4[4],G4[5],G4[6],G4[7]);
        *(float4*)(out + obase + 2*chs)     = make_float4(B4[0],B4[1],B4[2],B4[3]);
        *(float4*)(out + obase + 2*chs + 4) = make_float4(B4[4],B4[5],B4[6],B4[7]);
    }
}

extern "C" void kernel_launch(void* const* d_in, const int* in_sizes, int n_in,
                              void* d_out, int out_size, void* d_ws, size_t ws_size,
                              hipStream_t stream) {
    (void)in_sizes; (void)n_in; (void)out_size; (void)ws_size;
    const float* in  = (const float*)d_in[0];
    const float* qz  = (const float*)d_in[1];
    const float* dm  = (const float*)d_in[2];
    double* ws = (double*)d_ws;
    float* out = (float*)d_out;
    hipLaunchKernelGGL(jpeg_tables, dim3(1), dim3(256), 0, stream, qz, dm, ws);
    hipLaunchKernelGGL(jpeg_kernel, dim3(4096), dim3(256), 0, stream,
                       in, (const double*)ws, out);
}